// Round 6
// baseline (1348.375 us; speedup 1.0000x reference)
//
#include <hip/hip_runtime.h>
#include <hip/hip_fp16.h>
#include <hip/hip_cooperative_groups.h>

namespace cg = cooperative_groups;

#define N_NODES 50000
#define N_FEAT  128
#define HID     64
#define N_EDGES 800000
#define N_GRAPHS 64
#define MAXDEG  64
#define BN_EPS  1e-5f

struct Prm {
    const float* x; const int* ei; const int* batch;
    const float* W_in; const float* W1; const float* b1;
    const float* Ws; const float* bs;
    const float* bn_g; const float* bn_b; const float* bn_m; const float* bn_v;
    const float* lin_w; const float* lin_b;
    float* out;
    int* fill; unsigned short* colp; __half* g16; float* h;
    float* sums; float* cnts;
};

// ---- fp16 row accumulate: 8 halves (one uint4) -> 8 fp32 accumulators ----
__device__ __forceinline__ void acc8(const uint4 r, float* a) {
    float2 f0 = __half22float2(*(const __half2*)&r.x);
    float2 f1 = __half22float2(*(const __half2*)&r.y);
    float2 f2 = __half22float2(*(const __half2*)&r.z);
    float2 f3 = __half22float2(*(const __half2*)&r.w);
    a[0] += f0.x; a[1] += f0.y; a[2] += f1.x; a[3] += f1.y;
    a[4] += f2.x; a[5] += f2.y; a[6] += f3.x; a[7] += f3.y;
}

__device__ __forceinline__ int lowerb(const int* __restrict__ b, int val) {
    int lo = 0, hi = N_NODES;
    while (lo < hi) {
        int mid = (lo + hi) >> 1;
        if (b[mid] < val) lo = mid + 1; else hi = mid;
    }
    return lo;
}

// ---- GEMM for one virtual block of 40 nodes, K-chunked by 64 ----
// WT: [16][65] float4 (k4-major, +1 pad); XS: [40][16] float4.
template <int K, bool SCALE, bool HOUT>
__device__ __forceinline__ void gemm_vb(int vb, const float* __restrict__ in,
                                        const float* __restrict__ W,
                                        const int* __restrict__ fill,
                                        float* __restrict__ outf,
                                        __half* __restrict__ outh,
                                        float4* WT, float4* XS, int t) {
    constexpr int K4 = K / 4;          // 32 or 16
    const int base = vb * 40;
    const float4* Wv = (const float4*)W;
    const float4* xv = (const float4*)in;
    const int hh = t & 63;
    const int ng = t >> 6;
    float4 acc[10];
#pragma unroll
    for (int j = 0; j < 10; ++j) acc[j] = make_float4(0.f, 0.f, 0.f, 0.f);

    for (int c = 0; c < K4; c += 16) {
        __syncthreads();  // WAR on smem vs previous chunk/phase
        for (int i = t; i < HID * 16; i += 256) {
            int h2 = i >> 4, k4 = i & 15;
            WT[k4 * 65 + h2] = Wv[h2 * K4 + c + k4];
        }
        for (int i = t; i < 40 * 16; i += 256) {
            int nd = i >> 4, k4 = i & 15;
            XS[i] = xv[(base + nd) * K4 + c + k4];
        }
        __syncthreads();
#pragma unroll
        for (int k4 = 0; k4 < 16; ++k4) {
            float4 w = WT[k4 * 65 + hh];
#pragma unroll
            for (int j = 0; j < 10; ++j) {
                float4 xx = XS[(ng + 4 * j) * 16 + k4];
                acc[j].x += w.x * xx.x;
                acc[j].y += w.y * xx.y;
                acc[j].z += w.z * xx.z;
                acc[j].w += w.w * xx.w;
            }
        }
    }
#pragma unroll
    for (int j = 0; j < 10; ++j) {
        int node = base + ng + 4 * j;
        float s = SCALE ? rsqrtf((float)fill[node] + 1.0f) : 1.0f;
        float v = (acc[j].x + acc[j].y + acc[j].z + acc[j].w) * s;
        if (HOUT) outh[node * HID + hh] = __float2half(v);
        else      outf[node * HID + hh] = v;
    }
}

// ---- fp16 pull-gather + fused BN/ReLU/residual for one node ----
__device__ __forceinline__ void gather_vb(int n, int t,
                                          const __half* __restrict__ g16,
                                          const unsigned short* __restrict__ colp,
                                          const int* __restrict__ fill,
                                          const float* __restrict__ b,
                                          const float* __restrict__ gamma,
                                          const float* __restrict__ beta,
                                          const float* __restrict__ mean,
                                          const float* __restrict__ var,
                                          const float4* __restrict__ res4,
                                          float4* __restrict__ out4) {
    int lane = t & 63;
    int hh8 = lane & 7;
    int sub = lane >> 3;

    const uint4* gv = (const uint4*)g16;  // row = 8 x uint4
    int fl = fill[n];
    int deg = fl < MAXDEG ? fl : MAXDEG;
    const int base = n * MAXDEG;

    float a[8];
#pragma unroll
    for (int i = 0; i < 8; ++i) a[i] = 0.f;

    int j = sub;
    for (; j + 8 < deg; j += 16) {
        int c0 = colp[base + j];
        int c1 = colp[base + j + 8];
        uint4 r0 = gv[c0 * 8 + hh8];
        uint4 r1 = gv[c1 * 8 + hh8];
        acc8(r0, a);
        acc8(r1, a);
    }
    if (j < deg) {
        int c = colp[base + j];
        acc8(gv[c * 8 + hh8], a);
    }

#pragma unroll
    for (int m = 8; m <= 32; m <<= 1) {
#pragma unroll
        for (int i = 0; i < 8; ++i) a[i] += __shfl_xor(a[i], m);
    }

    if (sub == 0) {
        acc8(gv[n * 8 + hh8], a);  // self loop
        float di = rsqrtf((float)fl + 1.0f);
        float4 b0 = ((const float4*)b)[hh8 * 2],     b1 = ((const float4*)b)[hh8 * 2 + 1];
        float4 g0 = ((const float4*)gamma)[hh8 * 2], g1 = ((const float4*)gamma)[hh8 * 2 + 1];
        float4 e0 = ((const float4*)beta)[hh8 * 2],  e1 = ((const float4*)beta)[hh8 * 2 + 1];
        float4 m0 = ((const float4*)mean)[hh8 * 2],  m1 = ((const float4*)mean)[hh8 * 2 + 1];
        float4 v0 = ((const float4*)var)[hh8 * 2],   v1 = ((const float4*)var)[hh8 * 2 + 1];

        float bb[8] = {b0.x, b0.y, b0.z, b0.w, b1.x, b1.y, b1.z, b1.w};
        float gg[8] = {g0.x, g0.y, g0.z, g0.w, g1.x, g1.y, g1.z, g1.w};
        float ee[8] = {e0.x, e0.y, e0.z, e0.w, e1.x, e1.y, e1.z, e1.w};
        float mm[8] = {m0.x, m0.y, m0.z, m0.w, m1.x, m1.y, m1.z, m1.w};
        float vv[8] = {v0.x, v0.y, v0.z, v0.w, v1.x, v1.y, v1.z, v1.w};

        float o[8];
#pragma unroll
        for (int i = 0; i < 8; ++i) {
            float val = (a[i] * di + bb[i] - mm[i]) * (gg[i] * rsqrtf(vv[i] + BN_EPS)) + ee[i];
            o[i] = fmaxf(val, 0.f);
        }
        if (res4) {
            float4 r0 = res4[n * 16 + hh8 * 2];
            float4 r1 = res4[n * 16 + hh8 * 2 + 1];
            o[0] += r0.x; o[1] += r0.y; o[2] += r0.z; o[3] += r0.w;
            o[4] += r1.x; o[5] += r1.y; o[6] += r1.z; o[7] += r1.w;
        }
        out4[n * 16 + hh8 * 2]     = make_float4(o[0], o[1], o[2], o[3]);
        out4[n * 16 + hh8 * 2 + 1] = make_float4(o[4], o[5], o[6], o[7]);
    }
}

__global__ __launch_bounds__(256, 4) void mega(Prm p) {
    cg::grid_group grid = cg::this_grid();
    const int t = threadIdx.x;
    const int gsz = gridDim.x;

    __shared__ float4 WT[16 * 65];
    __shared__ float4 XS[40 * 16];
    __shared__ float RED[4][HID];

    // P0: zero fill / sums
    for (int i = blockIdx.x * 256 + t; i < N_NODES; i += gsz * 256) p.fill[i] = 0;
    for (int i = blockIdx.x * 256 + t; i < N_GRAPHS * HID; i += gsz * 256) p.sums[i] = 0.f;
    grid.sync();

    // P1: padded bucket placement (uint16 entries)
    for (int e = blockIdx.x * 256 + t; e < N_EDGES; e += gsz * 256) {
        int s = p.ei[e];
        int d = p.ei[N_EDGES + e];
        int k = atomicAdd(&p.fill[d], 1);
        if (k < MAXDEG) p.colp[d * MAXDEG + k] = (unsigned short)s;
    }
    grid.sync();

    // P2: identity = x@W_in^T (fp32 -> h) and layer-1 GEMM (fp16 -> g16)
    for (int vb = blockIdx.x; vb < 2500; vb += gsz) {
        if (vb < 1250)
            gemm_vb<N_FEAT, false, false>(vb, p.x, p.W_in, p.fill, p.h, nullptr, WT, XS, t);
        else
            gemm_vb<N_FEAT, true, true>(vb - 1250, p.x, p.W1, p.fill, nullptr, p.g16, WT, XS, t);
    }
    grid.sync();

    // G1: gather + bn0 + relu + identity residual
    for (int vb = blockIdx.x; vb < N_NODES / 4; vb += gsz) {
        int n = vb * 4 + (t >> 6);
        gather_vb(n, t, p.g16, p.colp, p.fill, p.b1,
                  p.bn_g, p.bn_b, p.bn_m, p.bn_v,
                  (const float4*)p.h, (float4*)p.h);
    }

    // layers 2..5
    for (int L = 0; L < 4; ++L) {
        grid.sync();
        const float* Wl = p.Ws + L * HID * HID;
        for (int vb = blockIdx.x; vb < 1250; vb += gsz)
            gemm_vb<HID, true, true>(vb, p.h, Wl, p.fill, nullptr, p.g16, WT, XS, t);
        grid.sync();
        const float* bias = p.bs + L * HID;
        const float* ga = p.bn_g + (L + 1) * HID;
        const float* be = p.bn_b + (L + 1) * HID;
        const float* me = p.bn_m + (L + 1) * HID;
        const float* va = p.bn_v + (L + 1) * HID;
        const float4* res = (L < 3) ? (const float4*)p.h : nullptr;
        for (int vb = blockIdx.x; vb < N_NODES / 4; vb += gsz) {
            int n = vb * 4 + (t >> 6);
            gather_vb(n, t, p.g16, p.colp, p.fill, bias, ga, be, me, va, res, (float4*)p.h);
        }
    }
    grid.sync();

    // pool: 8 chunks per graph, segmented reduction over sorted batch
    for (int vb = blockIdx.x; vb < N_GRAPHS * 8; vb += gsz) {
        __syncthreads();
        int g = vb >> 3, c = vb & 7;
        int w = t >> 6, hh = t & 63;
        int start = lowerb(p.batch, g);
        int end = lowerb(p.batch, g + 1);
        int len = end - start;
        int cs = start + (int)(((long long)len * c) / 8);
        int ce = start + (int)(((long long)len * (c + 1)) / 8);
        float acc = 0.f;
        for (int n = cs + w; n < ce; n += 4) acc += p.h[n * HID + hh];
        RED[w][hh] = acc;
        __syncthreads();
        if (w == 0) {
            float tot = RED[0][hh] + RED[1][hh] + RED[2][hh] + RED[3][hh];
            atomicAdd(&p.sums[g * HID + hh], tot);
            if (hh == 0 && c == 0) p.cnts[g] = (float)len;
        }
    }
    grid.sync();

    // final linear
    for (int vb = blockIdx.x; vb < N_GRAPHS; vb += gsz) {
        if (t < 64) {
            float c = fmaxf(p.cnts[vb], 1.0f);
            float v = (p.sums[vb * HID + t] / c) * p.lin_w[t];
#pragma unroll
            for (int off = 32; off > 0; off >>= 1) v += __shfl_down(v, off);
            if (t == 0) p.out[vb] = v + p.lin_b[0];
        }
    }
}

extern "C" void kernel_launch(void* const* d_in, const int* in_sizes, int n_in,
                              void* d_out, int out_size, void* d_ws, size_t ws_size,
                              hipStream_t stream) {
    Prm p;
    p.x     = (const float*)d_in[0];
    p.ei    = (const int*)d_in[1];
    p.batch = (const int*)d_in[2];
    p.W_in  = (const float*)d_in[3];
    p.W1    = (const float*)d_in[4];
    p.b1    = (const float*)d_in[5];
    p.Ws    = (const float*)d_in[6];
    p.bs    = (const float*)d_in[7];
    p.bn_g  = (const float*)d_in[8];
    p.bn_b  = (const float*)d_in[9];
    p.bn_m  = (const float*)d_in[10];
    p.bn_v  = (const float*)d_in[11];
    p.lin_w = (const float*)d_in[12];
    p.lin_b = (const float*)d_in[13];
    p.out   = (float*)d_out;

    char* q = (char*)d_ws;
    p.fill = (int*)q;                       q += (size_t)50048 * 4;
    p.colp = (unsigned short*)q;            q += (size_t)N_NODES * MAXDEG * 2;
    p.g16  = (__half*)q;                    q += (size_t)N_NODES * HID * 2;
    p.h    = (float*)q;                     q += (size_t)N_NODES * HID * 4;
    p.sums = (float*)q;                     q += N_GRAPHS * HID * 4;
    p.cnts = (float*)q;

    int maxb = 0;
    if (hipOccupancyMaxActiveBlocksPerMultiprocessor(&maxb, (const void*)mega, 256, 0)
        != hipSuccess || maxb < 1)
        maxb = 2;
    int grid = maxb * 256;          // 256 CUs on MI355X
    if (grid > 1536) grid = 1536;

    void* args[] = { &p };
    hipLaunchCooperativeKernel((const void*)mega, dim3(grid), dim3(256),
                               args, 0, stream);
}

// Round 7
// 536.060 us; speedup vs baseline: 2.5153x; 2.5153x over previous
//
#include <hip/hip_runtime.h>
#include <hip/hip_fp16.h>

#define N_NODES 50000
#define N_FEAT  128
#define HID     64
#define N_EDGES 800000
#define N_GRAPHS 64
#define MAXDEG  64
#define BN_EPS  1e-5f
#define NB256(n) (((n) + 255) / 256)

// ---------------- zero fill counters ----------------
__global__ __launch_bounds__(256) void k_zero(int* fill) {
    int i = blockIdx.x * 256 + threadIdx.x;
    if (i < N_NODES) fill[i] = 0;
}

// ---------------- single-pass padded bucket placement (uint16) ----------------
__global__ __launch_bounds__(256) void k_place(const int* __restrict__ ei,
                                               int* fill, unsigned short* __restrict__ colp) {
    int e = blockIdx.x * 256 + threadIdx.x;
    if (e < N_EDGES) {
        int s = ei[e];
        int d = ei[N_EDGES + e];
        int k = atomicAdd(&fill[d], 1);
        if (k < MAXDEG) colp[d * MAXDEG + k] = (unsigned short)s;
    }
}

// ---------------- standalone GEMM (identity & layer-1): 40 nodes/block ----------------
template <int K, bool SCALE, bool HOUT>
__global__ __launch_bounds__(256) void k_gemm(const float* __restrict__ in,
                                              const float* __restrict__ W,
                                              const int* __restrict__ fill,
                                              float* __restrict__ outf,
                                              __half* __restrict__ outh) {
    constexpr int NPB = 40;
    constexpr int K4 = K / 4;
    __shared__ float4 Wt[K4 * 65];
    __shared__ float4 xs[NPB * K4];
    const int t = threadIdx.x;
    const int base = blockIdx.x * NPB;

    const float4* Wv = (const float4*)W;
    for (int i = t; i < HID * K4; i += 256) {
        int hh = i / K4, k4 = i - hh * K4;
        Wt[k4 * 65 + hh] = Wv[i];
    }
    const float4* xv = (const float4*)(in + (long long)base * K);
    for (int i = t; i < NPB * K4; i += 256) xs[i] = xv[i];
    __syncthreads();

    const int hh = t & 63;
    const int ng = t >> 6;
    float4 acc[10];
#pragma unroll
    for (int j = 0; j < 10; ++j) acc[j] = make_float4(0.f, 0.f, 0.f, 0.f);

#pragma unroll 4
    for (int k4 = 0; k4 < K4; ++k4) {
        float4 w = Wt[k4 * 65 + hh];
#pragma unroll
        for (int j = 0; j < 10; ++j) {
            float4 x = xs[(ng + 4 * j) * K4 + k4];
            acc[j].x += w.x * x.x;
            acc[j].y += w.y * x.y;
            acc[j].z += w.z * x.z;
            acc[j].w += w.w * x.w;
        }
    }
#pragma unroll
    for (int j = 0; j < 10; ++j) {
        int node = base + ng + 4 * j;
        float s = SCALE ? rsqrtf((float)fill[node] + 1.0f) : 1.0f;
        float v = (acc[j].x + acc[j].y + acc[j].z + acc[j].w) * s;
        if (HOUT) outh[node * HID + hh] = __float2half(v);
        else      outf[node * HID + hh] = v;
    }
}

// ---- fp16 row accumulate: 8 halves (one uint4) -> 8 fp32 accumulators ----
__device__ __forceinline__ void acc8(const uint4 r, float* a) {
    float2 f0 = __half22float2(*(const __half2*)&r.x);
    float2 f1 = __half22float2(*(const __half2*)&r.y);
    float2 f2 = __half22float2(*(const __half2*)&r.z);
    float2 f3 = __half22float2(*(const __half2*)&r.w);
    a[0] += f0.x; a[1] += f0.y; a[2] += f1.x; a[3] += f1.y;
    a[4] += f2.x; a[5] += f2.y; a[6] += f3.x; a[7] += f3.y;
}

// ---- gather + BN/ReLU/residual for one node; result -> o[8] on sub==0 lanes ----
__device__ __forceinline__ bool gather_node(int n, int lane,
                                            const __half* __restrict__ g16,
                                            const unsigned short* __restrict__ colp,
                                            const int* __restrict__ fill,
                                            const float* __restrict__ b,
                                            const float* __restrict__ gamma,
                                            const float* __restrict__ beta,
                                            const float* __restrict__ mean,
                                            const float* __restrict__ var,
                                            const float4* __restrict__ res4,
                                            float* o) {
    int hh8 = lane & 7;
    int sub = lane >> 3;
    const uint4* gv = (const uint4*)g16;  // row = 8 x uint4
    int fl = fill[n];
    int deg = fl < MAXDEG ? fl : MAXDEG;
    const int base = n * MAXDEG;

    float a[8];
#pragma unroll
    for (int i = 0; i < 8; ++i) a[i] = 0.f;

    int j = sub;
    for (; j + 8 < deg; j += 16) {
        int c0 = colp[base + j];
        int c1 = colp[base + j + 8];
        uint4 r0 = gv[c0 * 8 + hh8];
        uint4 r1 = gv[c1 * 8 + hh8];
        acc8(r0, a);
        acc8(r1, a);
    }
    if (j < deg) {
        int c = colp[base + j];
        acc8(gv[c * 8 + hh8], a);
    }

#pragma unroll
    for (int m = 8; m <= 32; m <<= 1) {
#pragma unroll
        for (int i = 0; i < 8; ++i) a[i] += __shfl_xor(a[i], m);
    }

    if (sub != 0) return false;

    acc8(gv[n * 8 + hh8], a);  // self loop
    float di = rsqrtf((float)fl + 1.0f);
    float4 b0 = ((const float4*)b)[hh8 * 2],     b1 = ((const float4*)b)[hh8 * 2 + 1];
    float4 g0 = ((const float4*)gamma)[hh8 * 2], g1 = ((const float4*)gamma)[hh8 * 2 + 1];
    float4 e0 = ((const float4*)beta)[hh8 * 2],  e1 = ((const float4*)beta)[hh8 * 2 + 1];
    float4 m0 = ((const float4*)mean)[hh8 * 2],  m1 = ((const float4*)mean)[hh8 * 2 + 1];
    float4 v0 = ((const float4*)var)[hh8 * 2],   v1 = ((const float4*)var)[hh8 * 2 + 1];

    float bb[8] = {b0.x, b0.y, b0.z, b0.w, b1.x, b1.y, b1.z, b1.w};
    float gg[8] = {g0.x, g0.y, g0.z, g0.w, g1.x, g1.y, g1.z, g1.w};
    float ee[8] = {e0.x, e0.y, e0.z, e0.w, e1.x, e1.y, e1.z, e1.w};
    float mm[8] = {m0.x, m0.y, m0.z, m0.w, m1.x, m1.y, m1.z, m1.w};
    float vv[8] = {v0.x, v0.y, v0.z, v0.w, v1.x, v1.y, v1.z, v1.w};

#pragma unroll
    for (int i = 0; i < 8; ++i) {
        float val = (a[i] * di + bb[i] - mm[i]) * (gg[i] * rsqrtf(vv[i] + BN_EPS)) + ee[i];
        o[i] = fmaxf(val, 0.f);
    }
    if (res4) {
        float4 r0 = res4[n * 16 + hh8 * 2];
        float4 r1 = res4[n * 16 + hh8 * 2 + 1];
        o[0] += r0.x; o[1] += r0.y; o[2] += r0.z; o[3] += r0.w;
        o[4] += r1.x; o[5] += r1.y; o[6] += r1.z; o[7] += r1.w;
    }
    return true;
}

// ---------------- fused: gather layer L (40 nodes) -> LDS -> GEMM layer L+1 ----------
// Reads gin (fp16, all-nodes random), writes h (own nodes) and gout (fp16, own nodes).
__global__ __launch_bounds__(256) void k_gather_gemm(const __half* __restrict__ gin,
                                                     const unsigned short* __restrict__ colp,
                                                     const int* __restrict__ fill,
                                                     const float* __restrict__ b,
                                                     const float* __restrict__ gamma,
                                                     const float* __restrict__ beta,
                                                     const float* __restrict__ mean,
                                                     const float* __restrict__ var,
                                                     const float4* __restrict__ res4,
                                                     float4* __restrict__ h4,
                                                     const float* __restrict__ W,
                                                     __half* __restrict__ gout) {
    __shared__ float4 WT[16 * 65];
    __shared__ float4 XS[40 * 16];
    const int t = threadIdx.x;
    const int lane = t & 63;
    const int w = t >> 6;
    const int base = blockIdx.x * 40;
    const int hh8 = lane & 7;

    // stage W while gathers are in flight (no dependency)
    const float4* Wv = (const float4*)W;
    for (int i = t; i < HID * 16; i += 256) {
        int h2 = i >> 4, k4 = i & 15;
        WT[k4 * 65 + h2] = Wv[i];
    }

    // gather phase: 4 waves x 10 rounds = 40 nodes
    for (int r = 0; r < 10; ++r) {
        int nd = r * 4 + w;
        int n = base + nd;
        float o[8];
        if (gather_node(n, lane, gin, colp, fill, b, gamma, beta, mean, var, res4, o)) {
            float4 lo = make_float4(o[0], o[1], o[2], o[3]);
            float4 hi = make_float4(o[4], o[5], o[6], o[7]);
            h4[n * 16 + hh8 * 2]     = lo;
            h4[n * 16 + hh8 * 2 + 1] = hi;
            XS[nd * 16 + hh8 * 2]     = lo;
            XS[nd * 16 + hh8 * 2 + 1] = hi;
        }
    }
    __syncthreads();

    // gemm phase: gout[n,hh] = rsqrt(fill+1) * sum_k XS[n,k] * W[hh,k]
    const int hh = lane;
    const int ng = w;
    float4 acc[10];
#pragma unroll
    for (int j = 0; j < 10; ++j) acc[j] = make_float4(0.f, 0.f, 0.f, 0.f);
#pragma unroll
    for (int k4 = 0; k4 < 16; ++k4) {
        float4 wv = WT[k4 * 65 + hh];
#pragma unroll
        for (int j = 0; j < 10; ++j) {
            float4 xx = XS[(ng + 4 * j) * 16 + k4];
            acc[j].x += wv.x * xx.x;
            acc[j].y += wv.y * xx.y;
            acc[j].z += wv.z * xx.z;
            acc[j].w += wv.w * xx.w;
        }
    }
#pragma unroll
    for (int j = 0; j < 10; ++j) {
        int node = base + ng + 4 * j;
        float s = rsqrtf((float)fill[node] + 1.0f);
        float v = (acc[j].x + acc[j].y + acc[j].z + acc[j].w) * s;
        gout[node * HID + hh] = __float2half(v);
    }
}

// ---------------- standalone final gather (layer 5, no residual, no next gemm) ----
__global__ __launch_bounds__(256) void k_gather_post(const __half* __restrict__ gin,
                                                     const unsigned short* __restrict__ colp,
                                                     const int* __restrict__ fill,
                                                     const float* __restrict__ b,
                                                     const float* __restrict__ gamma,
                                                     const float* __restrict__ beta,
                                                     const float* __restrict__ mean,
                                                     const float* __restrict__ var,
                                                     float4* __restrict__ out4) {
    int n = blockIdx.x * 4 + (threadIdx.x >> 6);
    int lane = threadIdx.x & 63;
    if (n >= N_NODES) return;
    float o[8];
    if (gather_node(n, lane, gin, colp, fill, b, gamma, beta, mean, var, nullptr, o)) {
        int hh8 = lane & 7;
        out4[n * 16 + hh8 * 2]     = make_float4(o[0], o[1], o[2], o[3]);
        out4[n * 16 + hh8 * 2 + 1] = make_float4(o[4], o[5], o[6], o[7]);
    }
}

// ---------------- pool + final linear: one block per graph, no atomics ----------------
__device__ __forceinline__ int lowerb(const int* __restrict__ b, int val) {
    int lo = 0, hi = N_NODES;
    while (lo < hi) {
        int mid = (lo + hi) >> 1;
        if (b[mid] < val) lo = mid + 1; else hi = mid;
    }
    return lo;
}

__global__ __launch_bounds__(256) void k_poolfinal(const float* __restrict__ h,
                                                   const int* __restrict__ batch,
                                                   const float* __restrict__ lin_w,
                                                   const float* __restrict__ lin_b,
                                                   float* __restrict__ out) {
    __shared__ float red[4][HID];
    int g = blockIdx.x;
    int w = threadIdx.x >> 6;
    int hh = threadIdx.x & 63;
    int start = lowerb(batch, g);
    int end = lowerb(batch, g + 1);
    int len = end - start;
    float acc = 0.f;
    for (int n = start + w; n < end; n += 4) acc += h[n * HID + hh];
    red[w][hh] = acc;
    __syncthreads();
    if (w == 0) {
        float c = fmaxf((float)len, 1.0f);
        float v = ((red[0][hh] + red[1][hh] + red[2][hh] + red[3][hh]) / c) * lin_w[hh];
#pragma unroll
        for (int off = 32; off > 0; off >>= 1) v += __shfl_down(v, off);
        if (hh == 0) out[g] = v + lin_b[0];
    }
}

extern "C" void kernel_launch(void* const* d_in, const int* in_sizes, int n_in,
                              void* d_out, int out_size, void* d_ws, size_t ws_size,
                              hipStream_t stream) {
    const float* x     = (const float*)d_in[0];
    const int*   ei    = (const int*)d_in[1];
    const int*   batch = (const int*)d_in[2];
    const float* W_in  = (const float*)d_in[3];
    const float* W1    = (const float*)d_in[4];
    const float* b1    = (const float*)d_in[5];
    const float* Ws    = (const float*)d_in[6];
    const float* bs_   = (const float*)d_in[7];
    const float* bn_g  = (const float*)d_in[8];
    const float* bn_b  = (const float*)d_in[9];
    const float* bn_m  = (const float*)d_in[10];
    const float* bn_v  = (const float*)d_in[11];
    const float* lin_w = (const float*)d_in[12];
    const float* lin_b = (const float*)d_in[13];
    float* out = (float*)d_out;

    char* q = (char*)d_ws;
    int*            fill = (int*)q;             q += (size_t)50048 * 4;
    unsigned short* colp = (unsigned short*)q;  q += (size_t)N_NODES * MAXDEG * 2;
    __half*         g16a = (__half*)q;          q += (size_t)N_NODES * HID * 2;
    __half*         g16b = (__half*)q;          q += (size_t)N_NODES * HID * 2;
    float*          h    = (float*)q;           q += (size_t)N_NODES * HID * 4;

    const int NB_N  = NB256(N_NODES);
    const int NB_E  = NB256(N_EDGES);
    const int NB_GM = N_NODES / 40;       // 1250
    const int NB_GA = (N_NODES + 3) / 4;  // 12500
    float4* h4 = (float4*)h;

    // adjacency
    k_zero<<<NB_N, 256, 0, stream>>>(fill);
    k_place<<<NB_E, 256, 0, stream>>>(ei, fill, colp);

    // identity (fp32 -> h) and layer-1 gemm (fp16 -> g16a)
    k_gemm<N_FEAT, false, false><<<NB_GM, 256, 0, stream>>>(x, W_in, fill, h, nullptr);
    k_gemm<N_FEAT, true, true><<<NB_GM, 256, 0, stream>>>(x, W1, fill, nullptr, g16a);

    // fused gather_L + gemm_{L+1}, double-buffered g16
    __half* bufs[2] = { g16a, g16b };
    for (int L = 0; L < 4; ++L) {
        const float* bias = (L == 0) ? b1 : bs_ + (L - 1) * HID;
        k_gather_gemm<<<NB_GM, 256, 0, stream>>>(
            bufs[L & 1], colp, fill, bias,
            bn_g + L * HID, bn_b + L * HID, bn_m + L * HID, bn_v + L * HID,
            (L == 0) ? (const float4*)h : (const float4*)h,  // residual = current h
            h4, Ws + L * HID * HID, bufs[(L + 1) & 1]);
    }

    // layer 5 gather (bn4, bias bs[3], no residual)
    k_gather_post<<<NB_GA, 256, 0, stream>>>(bufs[0], colp, fill, bs_ + 3 * HID,
                                             bn_g + 4 * HID, bn_b + 4 * HID,
                                             bn_m + 4 * HID, bn_v + 4 * HID, h4);

    // pool + final
    k_poolfinal<<<N_GRAPHS, 256, 0, stream>>>(h, batch, lin_w, lin_b, out);
}

// Round 8
// 450.903 us; speedup vs baseline: 2.9904x; 1.1889x over previous
//
#include <hip/hip_runtime.h>
#include <hip/hip_fp16.h>

#define N_NODES 50000
#define N_FEAT  128
#define HID     64
#define N_EDGES 800000
#define N_GRAPHS 64
#define MAXDEG  64
#define BN_EPS  1e-5f
#define NB256(n) (((n) + 255) / 256)

// ---------------- zero fill counters ----------------
__global__ __launch_bounds__(256) void k_zero(int* fill) {
    int i = blockIdx.x * 256 + threadIdx.x;
    if (i < N_NODES) fill[i] = 0;
}

// ---------------- single-pass padded bucket placement (uint16 entries) ----------------
__global__ __launch_bounds__(256) void k_place(const int* __restrict__ ei,
                                               int* fill, unsigned short* __restrict__ colp) {
    int e = blockIdx.x * 256 + threadIdx.x;
    if (e < N_EDGES) {
        int s = ei[e];
        int d = ei[N_EDGES + e];
        int k = atomicAdd(&fill[d], 1);
        if (k < MAXDEG) colp[d * MAXDEG + k] = (unsigned short)s;
    }
}

// ---------------- dual GEMM (K=128): h = x@W_in^T (fp32), g16 = dinv*(x@W1^T) (fp16) ----
// 40 nodes/block. x staged once (20 KB); weights chunk-staged 64-k at a time.
__global__ __launch_bounds__(256) void k_dualgemm(const float* __restrict__ x,
                                                  const float* __restrict__ W_in,
                                                  const float* __restrict__ W1,
                                                  const int* __restrict__ fill,
                                                  float* __restrict__ h,
                                                  __half* __restrict__ g16) {
    __shared__ float4 xs[40 * 32];          // node-major: xs[nd*32 + k4]
    __shared__ float4 WtA[16 * 65];
    __shared__ float4 WtB[16 * 65];
    const int t = threadIdx.x;
    const int base = blockIdx.x * 40;

    const float4* xv = (const float4*)(x + (long long)base * N_FEAT);
    for (int i = t; i < 40 * 32; i += 256) xs[i] = xv[i];

    const float4* WAv = (const float4*)W_in;
    const float4* WBv = (const float4*)W1;

    const int hh = t & 63;
    const int ng = t >> 6;
    float4 a0[10], a1[10];
#pragma unroll
    for (int j = 0; j < 10; ++j) {
        a0[j] = make_float4(0.f, 0.f, 0.f, 0.f);
        a1[j] = make_float4(0.f, 0.f, 0.f, 0.f);
    }

    for (int c = 0; c < 2; ++c) {
        __syncthreads();  // WAR on Wt chunks (and xs before first MAC)
        for (int i = t; i < HID * 16; i += 256) {
            int h2 = i >> 4, k4 = i & 15;
            WtA[k4 * 65 + h2] = WAv[h2 * 32 + c * 16 + k4];
            WtB[k4 * 65 + h2] = WBv[h2 * 32 + c * 16 + k4];
        }
        __syncthreads();
#pragma unroll
        for (int k4 = 0; k4 < 16; ++k4) {
            float4 wa = WtA[k4 * 65 + hh];
            float4 wb = WtB[k4 * 65 + hh];
#pragma unroll
            for (int j = 0; j < 10; ++j) {
                float4 xx = xs[(ng + 4 * j) * 32 + c * 16 + k4];
                a0[j].x += wa.x * xx.x; a0[j].y += wa.y * xx.y;
                a0[j].z += wa.z * xx.z; a0[j].w += wa.w * xx.w;
                a1[j].x += wb.x * xx.x; a1[j].y += wb.y * xx.y;
                a1[j].z += wb.z * xx.z; a1[j].w += wb.w * xx.w;
            }
        }
    }
#pragma unroll
    for (int j = 0; j < 10; ++j) {
        int node = base + ng + 4 * j;
        h[node * HID + hh] = a0[j].x + a0[j].y + a0[j].z + a0[j].w;
        float s = rsqrtf((float)fill[node] + 1.0f);
        float v = (a1[j].x + a1[j].y + a1[j].z + a1[j].w) * s;
        g16[node * HID + hh] = __float2half(v);
    }
}

// ---------------- GEMM (K=64): g16 = dinv * (h @ W^T), fp16 out ----------------
__global__ __launch_bounds__(256) void k_gemm64(const float* __restrict__ in,
                                                const float* __restrict__ W,
                                                const int* __restrict__ fill,
                                                __half* __restrict__ outh) {
    constexpr int K4 = 16;
    __shared__ float4 Wt[K4 * 65];
    __shared__ float4 xs[40 * K4];
    const int t = threadIdx.x;
    const int base = blockIdx.x * 40;

    const float4* Wv = (const float4*)W;
    for (int i = t; i < HID * K4; i += 256) {
        int hh = i >> 4, k4 = i & 15;
        Wt[k4 * 65 + hh] = Wv[i];
    }
    const float4* xv = (const float4*)(in + (long long)base * HID);
    for (int i = t; i < 40 * K4; i += 256) xs[i] = xv[i];
    __syncthreads();

    const int hh = t & 63;
    const int ng = t >> 6;
    float4 acc[10];
#pragma unroll
    for (int j = 0; j < 10; ++j) acc[j] = make_float4(0.f, 0.f, 0.f, 0.f);

#pragma unroll
    for (int k4 = 0; k4 < K4; ++k4) {
        float4 w = Wt[k4 * 65 + hh];
#pragma unroll
        for (int j = 0; j < 10; ++j) {
            float4 x = xs[(ng + 4 * j) * K4 + k4];
            acc[j].x += w.x * x.x;
            acc[j].y += w.y * x.y;
            acc[j].z += w.z * x.z;
            acc[j].w += w.w * x.w;
        }
    }
#pragma unroll
    for (int j = 0; j < 10; ++j) {
        int node = base + ng + 4 * j;
        float s = rsqrtf((float)fill[node] + 1.0f);
        float v = (acc[j].x + acc[j].y + acc[j].z + acc[j].w) * s;
        outh[node * HID + hh] = __float2half(v);
    }
}

// ---- fp16 row accumulate: 8 halves (one uint4) -> 8 fp32 accumulators ----
__device__ __forceinline__ void acc8(const uint4 r, float* a) {
    float2 f0 = __half22float2(*(const __half2*)&r.x);
    float2 f1 = __half22float2(*(const __half2*)&r.y);
    float2 f2 = __half22float2(*(const __half2*)&r.z);
    float2 f3 = __half22float2(*(const __half2*)&r.w);
    a[0] += f0.x; a[1] += f0.y; a[2] += f1.x; a[3] += f1.y;
    a[4] += f2.x; a[5] += f2.y; a[6] += f3.x; a[7] += f3.y;
}

// ---------------- fp16 pull-gather + fused BN/ReLU/[residual] ----------------
// wave = 1 node; 12500 blocks of 4 waves (max TLP — do not fuse this down).
__global__ __launch_bounds__(256) void k_gather_post(const __half* __restrict__ g16,
                                                     const unsigned short* __restrict__ colp,
                                                     const int* __restrict__ fill,
                                                     const float* __restrict__ b,
                                                     const float* __restrict__ gamma,
                                                     const float* __restrict__ beta,
                                                     const float* __restrict__ mean,
                                                     const float* __restrict__ var,
                                                     const float4* __restrict__ res4,
                                                     float4* __restrict__ out4) {
    int n = blockIdx.x * 4 + (threadIdx.x >> 6);
    int lane = threadIdx.x & 63;
    int hh8 = lane & 7;
    int sub = lane >> 3;
    if (n >= N_NODES) return;

    const uint4* gv = (const uint4*)g16;  // row = 8 x uint4 (128 B)
    int fl = fill[n];
    int deg = fl < MAXDEG ? fl : MAXDEG;
    const int base = n * MAXDEG;

    float a[8];
#pragma unroll
    for (int i = 0; i < 8; ++i) a[i] = 0.f;

    int j = sub;
    for (; j + 8 < deg; j += 16) {
        int c0 = colp[base + j];
        int c1 = colp[base + j + 8];
        uint4 r0 = gv[c0 * 8 + hh8];
        uint4 r1 = gv[c1 * 8 + hh8];
        acc8(r0, a);
        acc8(r1, a);
    }
    if (j < deg) {
        int c = colp[base + j];
        acc8(gv[c * 8 + hh8], a);
    }

#pragma unroll
    for (int m = 8; m <= 32; m <<= 1) {
#pragma unroll
        for (int i = 0; i < 8; ++i) a[i] += __shfl_xor(a[i], m);
    }

    if (sub != 0) return;

    acc8(gv[n * 8 + hh8], a);  // self loop
    float di = rsqrtf((float)fl + 1.0f);
    float4 b0 = ((const float4*)b)[hh8 * 2],     b1 = ((const float4*)b)[hh8 * 2 + 1];
    float4 g0 = ((const float4*)gamma)[hh8 * 2], g1 = ((const float4*)gamma)[hh8 * 2 + 1];
    float4 e0 = ((const float4*)beta)[hh8 * 2],  e1 = ((const float4*)beta)[hh8 * 2 + 1];
    float4 m0 = ((const float4*)mean)[hh8 * 2],  m1 = ((const float4*)mean)[hh8 * 2 + 1];
    float4 v0 = ((const float4*)var)[hh8 * 2],   v1 = ((const float4*)var)[hh8 * 2 + 1];

    float bb[8] = {b0.x, b0.y, b0.z, b0.w, b1.x, b1.y, b1.z, b1.w};
    float gg[8] = {g0.x, g0.y, g0.z, g0.w, g1.x, g1.y, g1.z, g1.w};
    float ee[8] = {e0.x, e0.y, e0.z, e0.w, e1.x, e1.y, e1.z, e1.w};
    float mm[8] = {m0.x, m0.y, m0.z, m0.w, m1.x, m1.y, m1.z, m1.w};
    float vv[8] = {v0.x, v0.y, v0.z, v0.w, v1.x, v1.y, v1.z, v1.w};

    float o[8];
#pragma unroll
    for (int i = 0; i < 8; ++i) {
        float val = (a[i] * di + bb[i] - mm[i]) * (gg[i] * rsqrtf(vv[i] + BN_EPS)) + ee[i];
        o[i] = fmaxf(val, 0.f);
    }
    if (res4) {
        float4 r0 = res4[n * 16 + hh8 * 2];
        float4 r1 = res4[n * 16 + hh8 * 2 + 1];
        o[0] += r0.x; o[1] += r0.y; o[2] += r0.z; o[3] += r0.w;
        o[4] += r1.x; o[5] += r1.y; o[6] += r1.z; o[7] += r1.w;
    }
    out4[n * 16 + hh8 * 2]     = make_float4(o[0], o[1], o[2], o[3]);
    out4[n * 16 + hh8 * 2 + 1] = make_float4(o[4], o[5], o[6], o[7]);
}

// ---------------- pool + final linear: one 1024-thread block per graph ----------------
__device__ __forceinline__ int lowerb(const int* __restrict__ b, int val) {
    int lo = 0, hi = N_NODES;
    while (lo < hi) {
        int mid = (lo + hi) >> 1;
        if (b[mid] < val) lo = mid + 1; else hi = mid;
    }
    return lo;
}

__global__ __launch_bounds__(1024) void k_poolfinal(const float* __restrict__ h,
                                                    const int* __restrict__ batch,
                                                    const float* __restrict__ lin_w,
                                                    const float* __restrict__ lin_b,
                                                    float* __restrict__ out) {
    __shared__ float red[16][HID];
    int g = blockIdx.x;
    int w = threadIdx.x >> 6;
    int hh = threadIdx.x & 63;
    int start = lowerb(batch, g);
    int end = lowerb(batch, g + 1);
    int len = end - start;
    float acc = 0.f;
    for (int n = start + w; n < end; n += 16) acc += h[n * HID + hh];
    red[w][hh] = acc;
    __syncthreads();
    if (w == 0) {
        float s = 0.f;
#pragma unroll
        for (int i = 0; i < 16; ++i) s += red[i][hh];
        float c = fmaxf((float)len, 1.0f);
        float v = (s / c) * lin_w[hh];
#pragma unroll
        for (int off = 32; off > 0; off >>= 1) v += __shfl_down(v, off);
        if (hh == 0) out[g] = v + lin_b[0];
    }
}

extern "C" void kernel_launch(void* const* d_in, const int* in_sizes, int n_in,
                              void* d_out, int out_size, void* d_ws, size_t ws_size,
                              hipStream_t stream) {
    const float* x     = (const float*)d_in[0];
    const int*   ei    = (const int*)d_in[1];
    const int*   batch = (const int*)d_in[2];
    const float* W_in  = (const float*)d_in[3];
    const float* W1    = (const float*)d_in[4];
    const float* b1    = (const float*)d_in[5];
    const float* Ws    = (const float*)d_in[6];
    const float* bs_   = (const float*)d_in[7];
    const float* bn_g  = (const float*)d_in[8];
    const float* bn_b  = (const float*)d_in[9];
    const float* bn_m  = (const float*)d_in[10];
    const float* bn_v  = (const float*)d_in[11];
    const float* lin_w = (const float*)d_in[12];
    const float* lin_b = (const float*)d_in[13];
    float* out = (float*)d_out;

    char* q = (char*)d_ws;
    int*            fill = (int*)q;             q += (size_t)50048 * 4;
    unsigned short* colp = (unsigned short*)q;  q += (size_t)N_NODES * MAXDEG * 2;
    __half*         g16  = (__half*)q;          q += (size_t)N_NODES * HID * 2;
    float*          h    = (float*)q;           q += (size_t)N_NODES * HID * 4;

    const int NB_N  = NB256(N_NODES);
    const int NB_E  = NB256(N_EDGES);
    const int NB_GM = N_NODES / 40;       // 1250
    const int NB_GA = (N_NODES + 3) / 4;  // 12500
    float4* h4 = (float4*)h;

    // adjacency
    k_zero<<<NB_N, 256, 0, stream>>>(fill);
    k_place<<<NB_E, 256, 0, stream>>>(ei, fill, colp);

    // identity (fp32 -> h) + layer-1 gemm (fp16 -> g16) in one pass over x
    k_dualgemm<<<NB_GM, 256, 0, stream>>>(x, W_in, W1, fill, h, g16);

    // layer 1 gather: bn0, relu, + identity residual (in h)
    k_gather_post<<<NB_GA, 256, 0, stream>>>(g16, colp, fill, b1,
                                             bn_g, bn_b, bn_m, bn_v,
                                             (const float4*)h, h4);

    // layers 2-4 (residual)
    for (int i = 0; i < 3; ++i) {
        k_gemm64<<<NB_GM, 256, 0, stream>>>(h, Ws + i * HID * HID, fill, g16);
        k_gather_post<<<NB_GA, 256, 0, stream>>>(g16, colp, fill, bs_ + i * HID,
                                                 bn_g + (i + 1) * HID, bn_b + (i + 1) * HID,
                                                 bn_m + (i + 1) * HID, bn_v + (i + 1) * HID,
                                                 (const float4*)h, h4);
    }

    // layer 5 (no residual)
    k_gemm64<<<NB_GM, 256, 0, stream>>>(h, Ws + 3 * HID * HID, fill, g16);
    k_gather_post<<<NB_GA, 256, 0, stream>>>(g16, colp, fill, bs_ + 3 * HID,
                                             bn_g + 4 * HID, bn_b + 4 * HID,
                                             bn_m + 4 * HID, bn_v + 4 * HID,
                                             nullptr, h4);

    // pool + final
    k_poolfinal<<<N_GRAPHS, 1024, 0, stream>>>(h, batch, lin_w, lin_b, out);
}

// Round 9
// 439.965 us; speedup vs baseline: 3.0647x; 1.0249x over previous
//
#include <hip/hip_runtime.h>
#include <hip/hip_fp16.h>

#define N_NODES 50000
#define N_FEAT  128
#define HID     64
#define N_EDGES 800000
#define N_GRAPHS 64
#define MAXDEG  64
#define BN_EPS  1e-5f
#define NB256(n) (((n) + 255) / 256)

// ---------------- zero fill counters ----------------
__global__ __launch_bounds__(256) void k_zero(int* fill) {
    int i = blockIdx.x * 256 + threadIdx.x;
    if (i < N_NODES) fill[i] = 0;
}

// ---------------- single-pass padded bucket placement (uint16 entries) ----------------
__global__ __launch_bounds__(256) void k_place(const int* __restrict__ ei,
                                               int* fill, unsigned short* __restrict__ colp) {
    int e = blockIdx.x * 256 + threadIdx.x;
    if (e < N_EDGES) {
        int s = ei[e];
        int d = ei[N_EDGES + e];
        int k = atomicAdd(&fill[d], 1);
        if (k < MAXDEG) colp[d * MAXDEG + k] = (unsigned short)s;
    }
}

// ---------------- GEMM: out[n,hh] = [dinv] * sum_k in[n,k]*W[hh,k] ----------------
// 40 nodes/block; x staged fully; W chunk-staged 16 float4-k at a time
// (LDS 37.1 KB @K=128, 26.9 KB @K=64 -> 4-5 blocks/CU).
template <int K, bool SCALE, bool HOUT>
__global__ __launch_bounds__(256) void k_gemm(const float* __restrict__ in,
                                              const float* __restrict__ W,
                                              const int* __restrict__ fill,
                                              float* __restrict__ outf,
                                              __half* __restrict__ outh) {
    constexpr int K4 = K / 4;
    __shared__ float4 Wt[16 * 65];
    __shared__ float4 xs[40 * K4];
    const int t = threadIdx.x;
    const int base = blockIdx.x * 40;

    const float4* xv = (const float4*)(in + (long long)base * K);
    for (int i = t; i < 40 * K4; i += 256) xs[i] = xv[i];

    const float4* Wv = (const float4*)W;
    const int hh = t & 63;
    const int ng = t >> 6;
    float4 acc[10];
#pragma unroll
    for (int j = 0; j < 10; ++j) acc[j] = make_float4(0.f, 0.f, 0.f, 0.f);

    for (int c = 0; c < K4; c += 16) {
        __syncthreads();  // WAR on Wt (also orders xs staging before first MAC)
        for (int i = t; i < HID * 16; i += 256) {
            int h2 = i >> 4, k4 = i & 15;
            Wt[k4 * 65 + h2] = Wv[h2 * K4 + c + k4];
        }
        __syncthreads();
#pragma unroll
        for (int k4 = 0; k4 < 16; ++k4) {
            float4 w = Wt[k4 * 65 + hh];
#pragma unroll
            for (int j = 0; j < 10; ++j) {
                float4 x = xs[(ng + 4 * j) * K4 + c + k4];
                acc[j].x += w.x * x.x;
                acc[j].y += w.y * x.y;
                acc[j].z += w.z * x.z;
                acc[j].w += w.w * x.w;
            }
        }
    }
#pragma unroll
    for (int j = 0; j < 10; ++j) {
        int node = base + ng + 4 * j;
        float s = SCALE ? rsqrtf((float)fill[node] + 1.0f) : 1.0f;
        float v = (acc[j].x + acc[j].y + acc[j].z + acc[j].w) * s;
        if (HOUT) outh[node * HID + hh] = __float2half(v);
        else      outf[node * HID + hh] = v;
    }
}

// ---- fp16 row accumulate: 8 halves (one uint4) -> 8 fp32 accumulators ----
__device__ __forceinline__ void acc8(const uint4 r, float* a) {
    float2 f0 = __half22float2(*(const __half2*)&r.x);
    float2 f1 = __half22float2(*(const __half2*)&r.y);
    float2 f2 = __half22float2(*(const __half2*)&r.z);
    float2 f3 = __half22float2(*(const __half2*)&r.w);
    a[0] += f0.x; a[1] += f0.y; a[2] += f1.x; a[3] += f1.y;
    a[4] += f2.x; a[5] += f2.y; a[6] += f3.x; a[7] += f3.y;
}

// ---------------- fp16 pull-gather + fused BN/ReLU/[residual] ----------------
// wave = 1 node (max TLP — do not fuse this down). Col ids prefetched with ONE
// coalesced 128B load (lane -> colp[n*64+lane]), distributed via shfl; row
// loads then stream with no address-dependency chain.
__global__ __launch_bounds__(256) void k_gather_post(const __half* __restrict__ g16,
                                                     const unsigned short* __restrict__ colp,
                                                     const int* __restrict__ fill,
                                                     const float* __restrict__ b,
                                                     const float* __restrict__ gamma,
                                                     const float* __restrict__ beta,
                                                     const float* __restrict__ mean,
                                                     const float* __restrict__ var,
                                                     const float4* __restrict__ res4,
                                                     float4* __restrict__ out4) {
    int n = blockIdx.x * 4 + (threadIdx.x >> 6);
    int lane = threadIdx.x & 63;
    int hh8 = lane & 7;
    int sub = lane >> 3;
    if (n >= N_NODES) return;

    const uint4* gv = (const uint4*)g16;  // row = 8 x uint4 (128 B)
    int fl = fill[n];
    int deg = fl < MAXDEG ? fl : MAXDEG;

    int call = (lane < deg) ? (int)colp[n * MAXDEG + lane] : 0;

    float a[8];
#pragma unroll
    for (int i = 0; i < 8; ++i) a[i] = 0.f;

    int nr = (deg + 7) >> 3;
#pragma unroll 4
    for (int r = 0; r < nr; ++r) {
        int j = r * 8 + sub;
        int c = __shfl(call, j);
        if (j < deg) acc8(gv[c * 8 + hh8], a);
    }

#pragma unroll
    for (int m = 8; m <= 32; m <<= 1) {
#pragma unroll
        for (int i = 0; i < 8; ++i) a[i] += __shfl_xor(a[i], m);
    }

    if (sub != 0) return;

    acc8(gv[n * 8 + hh8], a);  // self loop
    float di = rsqrtf((float)fl + 1.0f);
    float4 b0 = ((const float4*)b)[hh8 * 2],     b1 = ((const float4*)b)[hh8 * 2 + 1];
    float4 g0 = ((const float4*)gamma)[hh8 * 2], g1 = ((const float4*)gamma)[hh8 * 2 + 1];
    float4 e0 = ((const float4*)beta)[hh8 * 2],  e1 = ((const float4*)beta)[hh8 * 2 + 1];
    float4 m0 = ((const float4*)mean)[hh8 * 2],  m1 = ((const float4*)mean)[hh8 * 2 + 1];
    float4 v0 = ((const float4*)var)[hh8 * 2],   v1 = ((const float4*)var)[hh8 * 2 + 1];

    float bb[8] = {b0.x, b0.y, b0.z, b0.w, b1.x, b1.y, b1.z, b1.w};
    float gg[8] = {g0.x, g0.y, g0.z, g0.w, g1.x, g1.y, g1.z, g1.w};
    float ee[8] = {e0.x, e0.y, e0.z, e0.w, e1.x, e1.y, e1.z, e1.w};
    float mm[8] = {m0.x, m0.y, m0.z, m0.w, m1.x, m1.y, m1.z, m1.w};
    float vv[8] = {v0.x, v0.y, v0.z, v0.w, v1.x, v1.y, v1.z, v1.w};

    float o[8];
#pragma unroll
    for (int i = 0; i < 8; ++i) {
        float val = (a[i] * di + bb[i] - mm[i]) * (gg[i] * rsqrtf(vv[i] + BN_EPS)) + ee[i];
        o[i] = fmaxf(val, 0.f);
    }
    if (res4) {
        float4 r0 = res4[n * 16 + hh8 * 2];
        float4 r1 = res4[n * 16 + hh8 * 2 + 1];
        o[0] += r0.x; o[1] += r0.y; o[2] += r0.z; o[3] += r0.w;
        o[4] += r1.x; o[5] += r1.y; o[6] += r1.z; o[7] += r1.w;
    }
    out4[n * 16 + hh8 * 2]     = make_float4(o[0], o[1], o[2], o[3]);
    out4[n * 16 + hh8 * 2 + 1] = make_float4(o[4], o[5], o[6], o[7]);
}

// ---------------- pool + final linear: one 1024-thread block per graph ----------------
__device__ __forceinline__ int lowerb(const int* __restrict__ b, int val) {
    int lo = 0, hi = N_NODES;
    while (lo < hi) {
        int mid = (lo + hi) >> 1;
        if (b[mid] < val) lo = mid + 1; else hi = mid;
    }
    return lo;
}

__global__ __launch_bounds__(1024) void k_poolfinal(const float* __restrict__ h,
                                                    const int* __restrict__ batch,
                                                    const float* __restrict__ lin_w,
                                                    const float* __restrict__ lin_b,
                                                    float* __restrict__ out) {
    __shared__ float red[16][HID];
    int g = blockIdx.x;
    int w = threadIdx.x >> 6;
    int hh = threadIdx.x & 63;
    int start = lowerb(batch, g);
    int end = lowerb(batch, g + 1);
    int len = end - start;
    float acc = 0.f;
    for (int n = start + w; n < end; n += 16) acc += h[n * HID + hh];
    red[w][hh] = acc;
    __syncthreads();
    if (w == 0) {
        float s = 0.f;
#pragma unroll
        for (int i = 0; i < 16; ++i) s += red[i][hh];
        float c = fmaxf((float)len, 1.0f);
        float v = (s / c) * lin_w[hh];
#pragma unroll
        for (int off = 32; off > 0; off >>= 1) v += __shfl_down(v, off);
        if (hh == 0) out[g] = v + lin_b[0];
    }
}

extern "C" void kernel_launch(void* const* d_in, const int* in_sizes, int n_in,
                              void* d_out, int out_size, void* d_ws, size_t ws_size,
                              hipStream_t stream) {
    const float* x     = (const float*)d_in[0];
    const int*   ei    = (const int*)d_in[1];
    const int*   batch = (const int*)d_in[2];
    const float* W_in  = (const float*)d_in[3];
    const float* W1    = (const float*)d_in[4];
    const float* b1    = (const float*)d_in[5];
    const float* Ws    = (const float*)d_in[6];
    const float* bs_   = (const float*)d_in[7];
    const float* bn_g  = (const float*)d_in[8];
    const float* bn_b  = (const float*)d_in[9];
    const float* bn_m  = (const float*)d_in[10];
    const float* bn_v  = (const float*)d_in[11];
    const float* lin_w = (const float*)d_in[12];
    const float* lin_b = (const float*)d_in[13];
    float* out = (float*)d_out;

    char* q = (char*)d_ws;
    int*            fill = (int*)q;             q += (size_t)50048 * 4;
    unsigned short* colp = (unsigned short*)q;  q += (size_t)N_NODES * MAXDEG * 2;
    __half*         g16  = (__half*)q;          q += (size_t)N_NODES * HID * 2;
    float*          h    = (float*)q;           q += (size_t)N_NODES * HID * 4;

    const int NB_N  = NB256(N_NODES);
    const int NB_E  = NB256(N_EDGES);
    const int NB_GM = N_NODES / 40;       // 1250
    const int NB_GA = (N_NODES + 3) / 4;  // 12500
    float4* h4 = (float4*)h;

    // adjacency
    k_zero<<<NB_N, 256, 0, stream>>>(fill);
    k_place<<<NB_E, 256, 0, stream>>>(ei, fill, colp);

    // identity (fp32 -> h) and layer-1 gemm (fp16 -> g16)
    k_gemm<N_FEAT, false, false><<<NB_GM, 256, 0, stream>>>(x, W_in, fill, h, nullptr);
    k_gemm<N_FEAT, true, true><<<NB_GM, 256, 0, stream>>>(x, W1, fill, nullptr, g16);

    // layer 1 gather: bn0, relu, + identity residual (in h)
    k_gather_post<<<NB_GA, 256, 0, stream>>>(g16, colp, fill, b1,
                                             bn_g, bn_b, bn_m, bn_v,
                                             (const float4*)h, h4);

    // layers 2-4 (residual)
    for (int i = 0; i < 3; ++i) {
        k_gemm<HID, true, true><<<NB_GM, 256, 0, stream>>>(h, Ws + i * HID * HID, fill,
                                                           nullptr, g16);
        k_gather_post<<<NB_GA, 256, 0, stream>>>(g16, colp, fill, bs_ + i * HID,
                                                 bn_g + (i + 1) * HID, bn_b + (i + 1) * HID,
                                                 bn_m + (i + 1) * HID, bn_v + (i + 1) * HID,
                                                 (const float4*)h, h4);
    }

    // layer 5 (no residual)
    k_gemm<HID, true, true><<<NB_GM, 256, 0, stream>>>(h, Ws + 3 * HID * HID, fill,
                                                       nullptr, g16);
    k_gather_post<<<NB_GA, 256, 0, stream>>>(g16, colp, fill, bs_ + 3 * HID,
                                             bn_g + 4 * HID, bn_b + 4 * HID,
                                             bn_m + 4 * HID, bn_v + 4 * HID,
                                             nullptr, h4);

    // pool + final
    k_poolfinal<<<N_GRAPHS, 1024, 0, stream>>>(h, batch, lin_w, lin_b, out);
}